// Round 1
// baseline (273.743 us; speedup 1.0000x reference)
//
#include <hip/hip_runtime.h>

// GroupLasso collapses to: out = 0.12f * (sum(w*w) + sum(b*b))
//   ROOT_GAMMA + COARSE_GAMMA + FINE_GAMMA = 0.02 + 0.04 + 0.06 = 0.12
// (segment_sum summed over all segments == total sum; coarse_map is irrelevant)

constexpr int BLOCK = 256;
constexpr int GRID1 = 2048;

__device__ __forceinline__ float block_reduce(float acc) {
    // wave64 shuffle reduce
    #pragma unroll
    for (int off = 32; off > 0; off >>= 1)
        acc += __shfl_down(acc, off, 64);
    __shared__ float smem[BLOCK / 64];
    const int lane = threadIdx.x & 63;
    const int wave = threadIdx.x >> 6;
    if (lane == 0) smem[wave] = acc;
    __syncthreads();
    float s = 0.f;
    if (threadIdx.x == 0) {
        #pragma unroll
        for (int w = 0; w < BLOCK / 64; ++w) s += smem[w];
    }
    return s;  // valid only on thread 0
}

__global__ __launch_bounds__(BLOCK) void sq_partial_kernel(
    const float* __restrict__ w, long long nw,
    const float* __restrict__ b, long long nb,
    float* __restrict__ partials)
{
    const long long tid    = (long long)blockIdx.x * blockDim.x + threadIdx.x;
    const long long stride = (long long)gridDim.x * blockDim.x;

    float acc = 0.f;

    // weights: vectorized float4 body + scalar tail
    const long long nw4 = nw >> 2;
    const float4* w4 = reinterpret_cast<const float4*>(w);
    for (long long i = tid; i < nw4; i += stride) {
        float4 v = w4[i];
        acc = fmaf(v.x, v.x, acc);
        acc = fmaf(v.y, v.y, acc);
        acc = fmaf(v.z, v.z, acc);
        acc = fmaf(v.w, v.w, acc);
    }
    for (long long i = (nw4 << 2) + tid; i < nw; i += stride)
        acc = fmaf(w[i], w[i], acc);

    // bias: same treatment
    const long long nb4 = nb >> 2;
    const float4* b4 = reinterpret_cast<const float4*>(b);
    for (long long i = tid; i < nb4; i += stride) {
        float4 v = b4[i];
        acc = fmaf(v.x, v.x, acc);
        acc = fmaf(v.y, v.y, acc);
        acc = fmaf(v.z, v.z, acc);
        acc = fmaf(v.w, v.w, acc);
    }
    for (long long i = (nb4 << 2) + tid; i < nb; i += stride)
        acc = fmaf(b[i], b[i], acc);

    float s = block_reduce(acc);
    if (threadIdx.x == 0) partials[blockIdx.x] = s;
}

__global__ __launch_bounds__(BLOCK) void final_kernel(
    const float* __restrict__ partials, int n, float* __restrict__ out)
{
    float acc = 0.f;
    for (int i = threadIdx.x; i < n; i += BLOCK) acc += partials[i];
    float s = block_reduce(acc);
    if (threadIdx.x == 0) out[0] = 0.12f * s;
}

extern "C" void kernel_launch(void* const* d_in, const int* in_sizes, int n_in,
                              void* d_out, int out_size, void* d_ws, size_t ws_size,
                              hipStream_t stream) {
    const float* w = (const float*)d_in[0];   // fc_weights, NUM_FINE*FEAT_DIM fp32
    const float* b = (const float*)d_in[1];   // fc_bias, NUM_FINE fp32
    // d_in[2] (coarse_map) is mathematically irrelevant — see header comment.

    const long long nw = (long long)in_sizes[0];
    const long long nb = (long long)in_sizes[1];

    float* partials = (float*)d_ws;           // GRID1 floats of scratch
    float* out = (float*)d_out;

    sq_partial_kernel<<<GRID1, BLOCK, 0, stream>>>(w, nw, b, nb, partials);
    final_kernel<<<1, BLOCK, 0, stream>>>(partials, GRID1, out);
}